// Round 4
// baseline (101.205 us; speedup 1.0000x reference)
//
#include <hip/hip_runtime.h>

#define B_ 8
#define C_ 19
#define H_ 512
#define W_ 512
#define HW_ (H_*W_)
#define N_ (B_*HW_)
#define HW4 (HW_/4)          /* 65536 float4 per channel-plane */
#define N4 (N_/4)            /* 524288 */
#define CH4 (C_*HW4)
#define K_RANK 100000
#define NBINS 2048
#define RED_BLOCKS 256
#define MAIN_BLOCKS (N4/256) /* 2048 */

struct SelState { unsigned prefix; unsigned krem; float threshold; };

// ---------------- init: zero histograms + selection state ----------------
__global__ __launch_bounds__(256) void init_kernel(unsigned* __restrict__ hists,
                                                   SelState* __restrict__ st) {
    int i = blockIdx.x * blockDim.x + threadIdx.x;
    if (i < 3 * NBINS) hists[i] = 0u;
    if (i == 0) { st->prefix = 0u; st->krem = (unsigned)K_RANK; st->threshold = 0.7f; }
}

// ---------------- main: online-softmax CE, 4 pixels/thread, single pass ----------------
// Live state per thread is only 16 accumulators (m,s,ts,tl per component) so the
// compiler can pipeline the 38 float4 loads deeply without re-reading logits.
// Fuses: radix-select histogram pass 0 + speculative thr=0.7 masked block partials.
__global__ __launch_bounds__(256) void main_kernel(const float4* __restrict__ logits,
                                                   const float4* __restrict__ target,
                                                   float4* __restrict__ pred,
                                                   float4* __restrict__ lossv,
                                                   unsigned* __restrict__ h0,
                                                   double* __restrict__ spec) {
    __shared__ unsigned lh[NBINS];
    __shared__ double sd1[256], sd2[256];
    for (int i = threadIdx.x; i < NBINS; i += 256) lh[i] = 0u;
    __syncthreads();

    int n4  = blockIdx.x * 256 + threadIdx.x;      // grid is exactly MAIN_BLOCKS
    int b   = n4 >> 16;                            // n4 / HW4
    int hw4 = n4 & (HW4 - 1);
    size_t base = (size_t)b * (size_t)CH4 + (size_t)hw4;
    const float4* lp = logits + base;
    const float4* tp = target + base;

    float mx = -3.4e38f, my = -3.4e38f, mz = -3.4e38f, mw = -3.4e38f;
    float sx = 0.f, sy = 0.f, sz = 0.f, sw = 0.f;
    float tsx = 0.f, tsy = 0.f, tsz = 0.f, tsw = 0.f;
    float tlx = 0.f, tly = 0.f, tlz = 0.f, tlw = 0.f;
#pragma unroll
    for (int c = 0; c < C_; ++c) {
        float4 l = lp[(size_t)c * HW4];
        float4 t = tp[(size_t)c * HW4];
        float nx = fmaxf(mx, l.x), ny = fmaxf(my, l.y);
        float nz = fmaxf(mz, l.z), nw = fmaxf(mw, l.w);
        sx = fmaf(sx, __expf(mx - nx), __expf(l.x - nx)); mx = nx;
        sy = fmaf(sy, __expf(my - ny), __expf(l.y - ny)); my = ny;
        sz = fmaf(sz, __expf(mz - nz), __expf(l.z - nz)); mz = nz;
        sw = fmaf(sw, __expf(mw - nw), __expf(l.w - nw)); mw = nw;
        tsx += t.x; tsy += t.y; tsz += t.z; tsw += t.w;
        tlx = fmaf(t.x, l.x, tlx);
        tly = fmaf(t.y, l.y, tly);
        tlz = fmaf(t.z, l.z, tlz);
        tlw = fmaf(t.w, l.w, tlw);
    }

    float4 lo, pr;
    lo.x = tsx * (mx + __logf(sx)) - tlx;  pr.x = __expf(tlx - mx) / sx;
    lo.y = tsy * (my + __logf(sy)) - tly;  pr.y = __expf(tly - my) / sy;
    lo.z = tsz * (mz + __logf(sz)) - tlz;  pr.z = __expf(tlz - mz) / sz;
    lo.w = tsw * (mw + __logf(sw)) - tlw;  pr.w = __expf(tlw - mw) / sw;
    lossv[n4] = lo;
    pred[n4]  = pr;

    // fused histogram pass 0 (pred >= 0 so uint order == float order)
    atomicAdd(&lh[__float_as_uint(pr.x) >> 21], 1u);
    atomicAdd(&lh[__float_as_uint(pr.y) >> 21], 1u);
    atomicAdd(&lh[__float_as_uint(pr.z) >> 21], 1u);
    atomicAdd(&lh[__float_as_uint(pr.w) >> 21], 1u);

    // speculative thr == 0.7 masked partials (exact when kth <= 0.7)
    double sl = 0.0, sm = 0.0;
    if (pr.x < 0.7f) { sl += (double)lo.x; sm += 1.0; }
    if (pr.y < 0.7f) { sl += (double)lo.y; sm += 1.0; }
    if (pr.z < 0.7f) { sl += (double)lo.z; sm += 1.0; }
    if (pr.w < 0.7f) { sl += (double)lo.w; sm += 1.0; }
    int t = threadIdx.x;
    sd1[t] = sl; sd2[t] = sm;
    __syncthreads();                       // also orders lh atomics before flush
    for (int off = 128; off > 0; off >>= 1) {
        if (t < off) { sd1[t] += sd1[t + off]; sd2[t] += sd2[t + off]; }
        __syncthreads();
    }
    if (t == 0) { spec[2 * blockIdx.x] = sd1[0]; spec[2 * blockIdx.x + 1] = sd2[0]; }
    for (int i = t; i < NBINS; i += 256) {
        unsigned v = lh[i];
        if (v) atomicAdd(&h0[i], v);
    }
}

// ---------------- radix-select histogram passes 1,2 (float4 reads) ----------------
template <int PASS>
__global__ __launch_bounds__(256) void hist_kernel(const float4* __restrict__ pred,
                                                   unsigned* __restrict__ hist,
                                                   const SelState* __restrict__ st) {
    __shared__ unsigned lh[NBINS];
    for (int i = threadIdx.x; i < NBINS; i += blockDim.x) lh[i] = 0u;
    __syncthreads();
    unsigned prefix = st->prefix;
    int stride = gridDim.x * blockDim.x;
    for (int n = blockIdx.x * blockDim.x + threadIdx.x; n < N4; n += stride) {
        float4 p = pred[n];
        unsigned u0 = __float_as_uint(p.x), u1 = __float_as_uint(p.y);
        unsigned u2 = __float_as_uint(p.z), u3 = __float_as_uint(p.w);
        if (PASS == 1) {
            if ((u0 & 0xFFE00000u) == prefix) atomicAdd(&lh[(u0 >> 10) & 0x7FFu], 1u);
            if ((u1 & 0xFFE00000u) == prefix) atomicAdd(&lh[(u1 >> 10) & 0x7FFu], 1u);
            if ((u2 & 0xFFE00000u) == prefix) atomicAdd(&lh[(u2 >> 10) & 0x7FFu], 1u);
            if ((u3 & 0xFFE00000u) == prefix) atomicAdd(&lh[(u3 >> 10) & 0x7FFu], 1u);
        } else {
            if ((u0 & 0xFFFFFC00u) == prefix) atomicAdd(&lh[u0 & 0x3FFu], 1u);
            if ((u1 & 0xFFFFFC00u) == prefix) atomicAdd(&lh[u1 & 0x3FFu], 1u);
            if ((u2 & 0xFFFFFC00u) == prefix) atomicAdd(&lh[u2 & 0x3FFu], 1u);
            if ((u3 & 0xFFFFFC00u) == prefix) atomicAdd(&lh[u3 & 0x3FFu], 1u);
        }
    }
    __syncthreads();
    for (int i = threadIdx.x; i < NBINS; i += blockDim.x) {
        unsigned v = lh[i];
        if (v) atomicAdd(&hist[i], v);
    }
}

// ---------------- radix-select scan: find bin containing rank krem ----------------
template <int PASS>
__global__ __launch_bounds__(256) void scan_kernel(const unsigned* __restrict__ hist,
                                                   SelState* __restrict__ st) {
    __shared__ unsigned ssum[256];
    int t = threadIdx.x;
    unsigned k = st->krem;
    unsigned local[8];
    unsigned lsum = 0;
#pragma unroll
    for (int i = 0; i < 8; ++i) { local[i] = hist[t * 8 + i]; lsum += local[i]; }
    ssum[t] = lsum;
    __syncthreads();
    unsigned val = lsum;
    for (int off = 1; off < 256; off <<= 1) {   // Hillis-Steele inclusive scan
        unsigned other = (t >= off) ? ssum[t - off] : 0u;
        __syncthreads();
        val += other;
        ssum[t] = val;
        __syncthreads();
    }
    unsigned c = val - lsum;                    // exclusive prefix of this thread's 8 bins
#pragma unroll
    for (int i = 0; i < 8; ++i) {
        if (k >= c && k < c + local[i]) {       // exactly one (t,i) matches
            unsigned bin = (unsigned)(t * 8 + i);
            if (PASS == 0) { st->prefix = bin << 21; st->krem = k - c; }
            else if (PASS == 1) { st->prefix |= bin << 10; st->krem = k - c; }
            else {
                unsigned full = st->prefix | bin;
                st->threshold = fmaxf(__uint_as_float(full), 0.7f);
            }
        }
        c += local[i];
    }
}

// ---------------- fallback masked reduction (only when threshold != 0.7) ----------------
__global__ __launch_bounds__(256) void reduce_kernel(const float4* __restrict__ pred,
                                                     const float4* __restrict__ lossv,
                                                     const SelState* __restrict__ st,
                                                     double* __restrict__ partials) {
    float thr = st->threshold;
    if (thr == 0.7f) return;                   // spec partials from main_kernel are exact
    double sl = 0.0, sm = 0.0;
    int stride = gridDim.x * blockDim.x;
    for (int n = blockIdx.x * blockDim.x + threadIdx.x; n < N4; n += stride) {
        float4 p = pred[n];
        float4 lo = lossv[n];
        if (p.x < thr) { sl += (double)lo.x; sm += 1.0; }
        if (p.y < thr) { sl += (double)lo.y; sm += 1.0; }
        if (p.z < thr) { sl += (double)lo.z; sm += 1.0; }
        if (p.w < thr) { sl += (double)lo.w; sm += 1.0; }
    }
    __shared__ double s1[256], s2[256];
    int t = threadIdx.x;
    s1[t] = sl; s2[t] = sm;
    __syncthreads();
    for (int off = 128; off > 0; off >>= 1) {
        if (t < off) { s1[t] += s1[t + off]; s2[t] += s2[t + off]; }
        __syncthreads();
    }
    if (t == 0) { partials[2 * blockIdx.x] = s1[0]; partials[2 * blockIdx.x + 1] = s2[0]; }
}

__global__ __launch_bounds__(256) void final_kernel(const double* __restrict__ partials,
                                                    const double* __restrict__ spec,
                                                    const SelState* __restrict__ st,
                                                    float* __restrict__ out) {
    __shared__ double s1[256], s2[256];
    int t = threadIdx.x;
    double a = 0.0, b = 0.0;
    if (st->threshold == 0.7f) {
        for (int i = t; i < MAIN_BLOCKS; i += 256) { a += spec[2 * i]; b += spec[2 * i + 1]; }
    } else {
        a = partials[2 * t]; b = partials[2 * t + 1];   // RED_BLOCKS == 256
    }
    s1[t] = a; s2[t] = b;
    __syncthreads();
    for (int off = 128; off > 0; off >>= 1) {
        if (t < off) { s1[t] += s1[t + off]; s2[t] += s2[t + off]; }
        __syncthreads();
    }
    if (t == 0) out[0] = (float)(s1[0] / fmax(s2[0], 1.0));
}

extern "C" void kernel_launch(void* const* d_in, const int* in_sizes, int n_in,
                              void* d_out, int out_size, void* d_ws, size_t ws_size,
                              hipStream_t stream) {
    const float4* logits = (const float4*)d_in[0];
    const float4* target = (const float4*)d_in[1];
    float* out = (float*)d_out;

    char* ws = (char*)d_ws;
    float4*   pred     = (float4*)ws;                                    // 8 MiB
    float4*   lossv    = (float4*)(ws + (size_t)N_ * 4);                 // 8 MiB
    unsigned* hists    = (unsigned*)(ws + (size_t)N_ * 8);               // 24 KiB
    SelState* st       = (SelState*)(ws + (size_t)N_ * 8 + 3 * NBINS * 4);
    double*   partials = (double*)(ws + (size_t)N_ * 8 + 3 * NBINS * 4 + 64);          // 4 KiB
    double*   spec     = (double*)(ws + (size_t)N_ * 8 + 3 * NBINS * 4 + 64
                                      + (size_t)RED_BLOCKS * 2 * 8);                   // 32 KiB

    unsigned* h0 = hists;
    unsigned* h1 = hists + NBINS;
    unsigned* h2 = hists + 2 * NBINS;

    init_kernel<<<(3 * NBINS + 255) / 256, 256, 0, stream>>>(hists, st);
    main_kernel<<<MAIN_BLOCKS, 256, 0, stream>>>(logits, target, pred, lossv, h0, spec);
    scan_kernel<0><<<1, 256, 0, stream>>>(h0, st);
    hist_kernel<1><<<512, 256, 0, stream>>>(pred, h1, st);
    scan_kernel<1><<<1, 256, 0, stream>>>(h1, st);
    hist_kernel<2><<<512, 256, 0, stream>>>(pred, h2, st);
    scan_kernel<2><<<1, 256, 0, stream>>>(h2, st);
    reduce_kernel<<<RED_BLOCKS, 256, 0, stream>>>(pred, lossv, st, partials);
    final_kernel<<<1, 256, 0, stream>>>(partials, spec, st, out);
}

// Round 6
// 101.024 us; speedup vs baseline: 1.0018x; 1.0018x over previous
//
#include <hip/hip_runtime.h>

#define B_ 8
#define C_ 19
#define H_ 512
#define W_ 512
#define HW_ (H_*W_)
#define N_ (B_*HW_)
#define HW4 (HW_/4)          /* 65536 float4 per channel-plane */
#define N4 (N_/4)            /* 524288 */
#define CH4 (C_*HW4)
#define K_RANK 100000
#define NBINS 2048
#define RED_BLOCKS 256
#define MAIN_BLOCKS (N4/256) /* 2048 */

struct SelState { unsigned prefix; unsigned krem; float threshold; };

typedef float f32x4 __attribute__((ext_vector_type(4)));

__device__ __forceinline__ float4 ntload(const float4* p) {
    f32x4 v = __builtin_nontemporal_load((const f32x4*)p);
    return make_float4(v.x, v.y, v.z, v.w);
}

// ---------------- init: zero histograms + selection state ----------------
__global__ __launch_bounds__(256) void init_kernel(unsigned* __restrict__ hists,
                                                   SelState* __restrict__ st) {
    int i = blockIdx.x * blockDim.x + threadIdx.x;
    if (i < 3 * NBINS) hists[i] = 0u;
    if (i == 0) { st->prefix = 0u; st->krem = (unsigned)K_RANK; st->threshold = 0.7f; }
}

// ---------------- main: online-softmax CE, 4 pixels/thread, single pass ----------------
// Inputs are streamed with NON-TEMPORAL loads: they have zero intra-dispatch reuse and
// cyclically thrash the 256MB L3 (50% hit / 50% fill churn capped us at ~2.8 TB/s).
// Fuses: radix-select histogram pass 0 + speculative thr=0.7 masked block partials.
__global__ __launch_bounds__(256) void main_kernel(const float4* __restrict__ logits,
                                                   const float4* __restrict__ target,
                                                   float4* __restrict__ pred,
                                                   float4* __restrict__ lossv,
                                                   unsigned* __restrict__ h0,
                                                   double* __restrict__ spec) {
    __shared__ unsigned lh[NBINS];
    __shared__ double sd1[256], sd2[256];
    for (int i = threadIdx.x; i < NBINS; i += 256) lh[i] = 0u;
    __syncthreads();

    int n4  = blockIdx.x * 256 + threadIdx.x;      // grid is exactly MAIN_BLOCKS
    int b   = n4 >> 16;                            // n4 / HW4
    int hw4 = n4 & (HW4 - 1);
    size_t base = (size_t)b * (size_t)CH4 + (size_t)hw4;
    const float4* lp = logits + base;
    const float4* tp = target + base;

    float mx = -3.4e38f, my = -3.4e38f, mz = -3.4e38f, mw = -3.4e38f;
    float sx = 0.f, sy = 0.f, sz = 0.f, sw = 0.f;
    float tsx = 0.f, tsy = 0.f, tsz = 0.f, tsw = 0.f;
    float tlx = 0.f, tly = 0.f, tlz = 0.f, tlw = 0.f;
#pragma unroll
    for (int c = 0; c < C_; ++c) {
        float4 l = ntload(lp + (size_t)c * HW4);
        float4 t = ntload(tp + (size_t)c * HW4);
        float nx = fmaxf(mx, l.x), ny = fmaxf(my, l.y);
        float nz = fmaxf(mz, l.z), nw = fmaxf(mw, l.w);
        sx = fmaf(sx, __expf(mx - nx), __expf(l.x - nx)); mx = nx;
        sy = fmaf(sy, __expf(my - ny), __expf(l.y - ny)); my = ny;
        sz = fmaf(sz, __expf(mz - nz), __expf(l.z - nz)); mz = nz;
        sw = fmaf(sw, __expf(mw - nw), __expf(l.w - nw)); mw = nw;
        tsx += t.x; tsy += t.y; tsz += t.z; tsw += t.w;
        tlx = fmaf(t.x, l.x, tlx);
        tly = fmaf(t.y, l.y, tly);
        tlz = fmaf(t.z, l.z, tlz);
        tlw = fmaf(t.w, l.w, tlw);
    }

    float4 lo, pr;
    lo.x = tsx * (mx + __logf(sx)) - tlx;  pr.x = __expf(tlx - mx) / sx;
    lo.y = tsy * (my + __logf(sy)) - tly;  pr.y = __expf(tly - my) / sy;
    lo.z = tsz * (mz + __logf(sz)) - tlz;  pr.z = __expf(tlz - mz) / sz;
    lo.w = tsw * (mw + __logf(sw)) - tlw;  pr.w = __expf(tlw - mw) / sw;
    lossv[n4] = lo;
    pred[n4]  = pr;

    // fused histogram pass 0 (pred >= 0 so uint order == float order)
    atomicAdd(&lh[__float_as_uint(pr.x) >> 21], 1u);
    atomicAdd(&lh[__float_as_uint(pr.y) >> 21], 1u);
    atomicAdd(&lh[__float_as_uint(pr.z) >> 21], 1u);
    atomicAdd(&lh[__float_as_uint(pr.w) >> 21], 1u);

    // speculative thr == 0.7 masked partials (exact when kth <= 0.7)
    double sl = 0.0, sm = 0.0;
    if (pr.x < 0.7f) { sl += (double)lo.x; sm += 1.0; }
    if (pr.y < 0.7f) { sl += (double)lo.y; sm += 1.0; }
    if (pr.z < 0.7f) { sl += (double)lo.z; sm += 1.0; }
    if (pr.w < 0.7f) { sl += (double)lo.w; sm += 1.0; }
    int t = threadIdx.x;
    sd1[t] = sl; sd2[t] = sm;
    __syncthreads();                       // also orders lh atomics before flush
    for (int off = 128; off > 0; off >>= 1) {
        if (t < off) { sd1[t] += sd1[t + off]; sd2[t] += sd2[t + off]; }
        __syncthreads();
    }
    if (t == 0) { spec[2 * blockIdx.x] = sd1[0]; spec[2 * blockIdx.x + 1] = sd2[0]; }
    for (int i = t; i < NBINS; i += 256) {
        unsigned v = lh[i];
        if (v) atomicAdd(&h0[i], v);
    }
}

// ---------------- radix-select histogram passes 1,2 (float4 reads) ----------------
template <int PASS>
__global__ __launch_bounds__(256) void hist_kernel(const float4* __restrict__ pred,
                                                   unsigned* __restrict__ hist,
                                                   const SelState* __restrict__ st) {
    __shared__ unsigned lh[NBINS];
    for (int i = threadIdx.x; i < NBINS; i += blockDim.x) lh[i] = 0u;
    __syncthreads();
    unsigned prefix = st->prefix;
    int stride = gridDim.x * blockDim.x;
    for (int n = blockIdx.x * blockDim.x + threadIdx.x; n < N4; n += stride) {
        float4 p = pred[n];
        unsigned u0 = __float_as_uint(p.x), u1 = __float_as_uint(p.y);
        unsigned u2 = __float_as_uint(p.z), u3 = __float_as_uint(p.w);
        if (PASS == 1) {
            if ((u0 & 0xFFE00000u) == prefix) atomicAdd(&lh[(u0 >> 10) & 0x7FFu], 1u);
            if ((u1 & 0xFFE00000u) == prefix) atomicAdd(&lh[(u1 >> 10) & 0x7FFu], 1u);
            if ((u2 & 0xFFE00000u) == prefix) atomicAdd(&lh[(u2 >> 10) & 0x7FFu], 1u);
            if ((u3 & 0xFFE00000u) == prefix) atomicAdd(&lh[(u3 >> 10) & 0x7FFu], 1u);
        } else {
            if ((u0 & 0xFFFFFC00u) == prefix) atomicAdd(&lh[u0 & 0x3FFu], 1u);
            if ((u1 & 0xFFFFFC00u) == prefix) atomicAdd(&lh[u1 & 0x3FFu], 1u);
            if ((u2 & 0xFFFFFC00u) == prefix) atomicAdd(&lh[u2 & 0x3FFu], 1u);
            if ((u3 & 0xFFFFFC00u) == prefix) atomicAdd(&lh[u3 & 0x3FFu], 1u);
        }
    }
    __syncthreads();
    for (int i = threadIdx.x; i < NBINS; i += blockDim.x) {
        unsigned v = lh[i];
        if (v) atomicAdd(&hist[i], v);
    }
}

// ---------------- radix-select scan: find bin containing rank krem ----------------
template <int PASS>
__global__ __launch_bounds__(256) void scan_kernel(const unsigned* __restrict__ hist,
                                                   SelState* __restrict__ st) {
    __shared__ unsigned ssum[256];
    int t = threadIdx.x;
    unsigned k = st->krem;
    unsigned local[8];
    unsigned lsum = 0;
#pragma unroll
    for (int i = 0; i < 8; ++i) { local[i] = hist[t * 8 + i]; lsum += local[i]; }
    ssum[t] = lsum;
    __syncthreads();
    unsigned val = lsum;
    for (int off = 1; off < 256; off <<= 1) {   // Hillis-Steele inclusive scan
        unsigned other = (t >= off) ? ssum[t - off] : 0u;
        __syncthreads();
        val += other;
        ssum[t] = val;
        __syncthreads();
    }
    unsigned c = val - lsum;                    // exclusive prefix of this thread's 8 bins
#pragma unroll
    for (int i = 0; i < 8; ++i) {
        if (k >= c && k < c + local[i]) {       // exactly one (t,i) matches
            unsigned bin = (unsigned)(t * 8 + i);
            if (PASS == 0) { st->prefix = bin << 21; st->krem = k - c; }
            else if (PASS == 1) { st->prefix |= bin << 10; st->krem = k - c; }
            else {
                unsigned full = st->prefix | bin;
                st->threshold = fmaxf(__uint_as_float(full), 0.7f);
            }
        }
        c += local[i];
    }
}

// ---------------- fallback masked reduction (only when threshold != 0.7) ----------------
__global__ __launch_bounds__(256) void reduce_kernel(const float4* __restrict__ pred,
                                                     const float4* __restrict__ lossv,
                                                     const SelState* __restrict__ st,
                                                     double* __restrict__ partials) {
    float thr = st->threshold;
    if (thr == 0.7f) return;                   // spec partials from main_kernel are exact
    double sl = 0.0, sm = 0.0;
    int stride = gridDim.x * blockDim.x;
    for (int n = blockIdx.x * blockDim.x + threadIdx.x; n < N4; n += stride) {
        float4 p = pred[n];
        float4 lo = lossv[n];
        if (p.x < thr) { sl += (double)lo.x; sm += 1.0; }
        if (p.y < thr) { sl += (double)lo.y; sm += 1.0; }
        if (p.z < thr) { sl += (double)lo.z; sm += 1.0; }
        if (p.w < thr) { sl += (double)lo.w; sm += 1.0; }
    }
    __shared__ double s1[256], s2[256];
    int t = threadIdx.x;
    s1[t] = sl; s2[t] = sm;
    __syncthreads();
    for (int off = 128; off > 0; off >>= 1) {
        if (t < off) { s1[t] += s1[t + off]; s2[t] += s2[t + off]; }
        __syncthreads();
    }
    if (t == 0) { partials[2 * blockIdx.x] = s1[0]; partials[2 * blockIdx.x + 1] = s2[0]; }
}

__global__ __launch_bounds__(256) void final_kernel(const double* __restrict__ partials,
                                                    const double* __restrict__ spec,
                                                    const SelState* __restrict__ st,
                                                    float* __restrict__ out) {
    __shared__ double s1[256], s2[256];
    int t = threadIdx.x;
    double a = 0.0, b = 0.0;
    if (st->threshold == 0.7f) {
        for (int i = t; i < MAIN_BLOCKS; i += 256) { a += spec[2 * i]; b += spec[2 * i + 1]; }
    } else {
        a = partials[2 * t]; b = partials[2 * t + 1];   // RED_BLOCKS == 256
    }
    s1[t] = a; s2[t] = b;
    __syncthreads();
    for (int off = 128; off > 0; off >>= 1) {
        if (t < off) { s1[t] += s1[t + off]; s2[t] += s2[t + off]; }
        __syncthreads();
    }
    if (t == 0) out[0] = (float)(s1[0] / fmax(s2[0], 1.0));
}

extern "C" void kernel_launch(void* const* d_in, const int* in_sizes, int n_in,
                              void* d_out, int out_size, void* d_ws, size_t ws_size,
                              hipStream_t stream) {
    const float4* logits = (const float4*)d_in[0];
    const float4* target = (const float4*)d_in[1];
    float* out = (float*)d_out;

    char* ws = (char*)d_ws;
    float4*   pred     = (float4*)ws;                                    // 8 MiB
    float4*   lossv    = (float4*)(ws + (size_t)N_ * 4);                 // 8 MiB
    unsigned* hists    = (unsigned*)(ws + (size_t)N_ * 8);               // 24 KiB
    SelState* st       = (SelState*)(ws + (size_t)N_ * 8 + 3 * NBINS * 4);
    double*   partials = (double*)(ws + (size_t)N_ * 8 + 3 * NBINS * 4 + 64);          // 4 KiB
    double*   spec     = (double*)(ws + (size_t)N_ * 8 + 3 * NBINS * 4 + 64
                                      + (size_t)RED_BLOCKS * 2 * 8);                   // 32 KiB

    unsigned* h0 = hists;
    unsigned* h1 = hists + NBINS;
    unsigned* h2 = hists + 2 * NBINS;

    init_kernel<<<(3 * NBINS + 255) / 256, 256, 0, stream>>>(hists, st);
    main_kernel<<<MAIN_BLOCKS, 256, 0, stream>>>(logits, target, pred, lossv, h0, spec);
    scan_kernel<0><<<1, 256, 0, stream>>>(h0, st);
    hist_kernel<1><<<512, 256, 0, stream>>>(pred, h1, st);
    scan_kernel<1><<<1, 256, 0, stream>>>(h1, st);
    hist_kernel<2><<<512, 256, 0, stream>>>(pred, h2, st);
    scan_kernel<2><<<1, 256, 0, stream>>>(h2, st);
    reduce_kernel<<<RED_BLOCKS, 256, 0, stream>>>(pred, lossv, st, partials);
    final_kernel<<<1, 256, 0, stream>>>(partials, spec, st, out);
}

// Round 7
// 84.046 us; speedup vs baseline: 1.2042x; 1.2020x over previous
//
#include <hip/hip_runtime.h>
#include <hip/hip_cooperative_groups.h>

namespace cg = cooperative_groups;

#define B_ 8
#define C_ 19
#define H_ 512
#define W_ 512
#define HW_ (H_*W_)
#define N_ (B_*HW_)
#define HW4 (HW_/4)          /* 65536 float4 per channel-plane */
#define N4 (N_/4)            /* 524288 */
#define CH4 (C_*HW4)
#define K_RANK 100000
#define NBINS 2048
#define MAIN_BLOCKS (N4/256) /* 2048 */
#define SEL_BLOCKS 512

struct SelState { unsigned prefix; unsigned krem; float threshold; };

typedef float f32x4 __attribute__((ext_vector_type(4)));

__device__ __forceinline__ float4 ntload(const float4* p) {
    f32x4 v = __builtin_nontemporal_load((const f32x4*)p);
    return make_float4(v.x, v.y, v.z, v.w);
}

// ---------------- main: online-softmax CE, 4 pixels/thread, single pass ----------------
// Inputs streamed with non-temporal loads (zero intra-dispatch reuse).
// Emits per-block partials of { sum(loss * [pred<0.7]), count[pred<0.7] } -- exact final
// answer whenever kth-smallest pred < 0.7 (i.e. count >= K_RANK+1).
__global__ __launch_bounds__(256) void main_kernel(const float4* __restrict__ logits,
                                                   const float4* __restrict__ target,
                                                   float4* __restrict__ pred,
                                                   float4* __restrict__ lossv,
                                                   double* __restrict__ spec) {
    int n4  = blockIdx.x * 256 + threadIdx.x;      // grid is exactly MAIN_BLOCKS
    int b   = n4 >> 16;                            // n4 / HW4
    int hw4 = n4 & (HW4 - 1);
    size_t base = (size_t)b * (size_t)CH4 + (size_t)hw4;
    const float4* lp = logits + base;
    const float4* tp = target + base;

    float mx = -3.4e38f, my = -3.4e38f, mz = -3.4e38f, mw = -3.4e38f;
    float sx = 0.f, sy = 0.f, sz = 0.f, sw = 0.f;
    float tsx = 0.f, tsy = 0.f, tsz = 0.f, tsw = 0.f;
    float tlx = 0.f, tly = 0.f, tlz = 0.f, tlw = 0.f;
#pragma unroll
    for (int c = 0; c < C_; ++c) {
        float4 l = ntload(lp + (size_t)c * HW4);
        float4 t = ntload(tp + (size_t)c * HW4);
        float nx = fmaxf(mx, l.x), ny = fmaxf(my, l.y);
        float nz = fmaxf(mz, l.z), nw = fmaxf(mw, l.w);
        sx = fmaf(sx, __expf(mx - nx), __expf(l.x - nx)); mx = nx;
        sy = fmaf(sy, __expf(my - ny), __expf(l.y - ny)); my = ny;
        sz = fmaf(sz, __expf(mz - nz), __expf(l.z - nz)); mz = nz;
        sw = fmaf(sw, __expf(mw - nw), __expf(l.w - nw)); mw = nw;
        tsx += t.x; tsy += t.y; tsz += t.z; tsw += t.w;
        tlx = fmaf(t.x, l.x, tlx);
        tly = fmaf(t.y, l.y, tly);
        tlz = fmaf(t.z, l.z, tlz);
        tlw = fmaf(t.w, l.w, tlw);
    }

    float4 lo, pr;
    lo.x = tsx * (mx + __logf(sx)) - tlx;  pr.x = __expf(tlx - mx) / sx;
    lo.y = tsy * (my + __logf(sy)) - tly;  pr.y = __expf(tly - my) / sy;
    lo.z = tsz * (mz + __logf(sz)) - tlz;  pr.z = __expf(tlz - mz) / sz;
    lo.w = tsw * (mw + __logf(sw)) - tlw;  pr.w = __expf(tlw - mw) / sw;
    lossv[n4] = lo;
    pred[n4]  = pr;

    // speculative thr == 0.7 masked partials (exact when kth < 0.7)
    double sl = 0.0, sm = 0.0;
    if (pr.x < 0.7f) { sl += (double)lo.x; sm += 1.0; }
    if (pr.y < 0.7f) { sl += (double)lo.y; sm += 1.0; }
    if (pr.z < 0.7f) { sl += (double)lo.z; sm += 1.0; }
    if (pr.w < 0.7f) { sl += (double)lo.w; sm += 1.0; }

    __shared__ double sd1[256], sd2[256];
    int t = threadIdx.x;
    sd1[t] = sl; sd2[t] = sm;
    __syncthreads();
    for (int off = 128; off > 0; off >>= 1) {
        if (t < off) { sd1[t] += sd1[t + off]; sd2[t] += sd2[t + off]; }
        __syncthreads();
    }
    if (t == 0) { spec[2 * blockIdx.x] = sd1[0]; spec[2 * blockIdx.x + 1] = sd2[0]; }
}

// ---------------- radix-select helpers (used only on the fallback path) ----------------
template <int PASS>
__device__ __forceinline__ void hist_pass(unsigned* lh, const float4* __restrict__ pred,
                                          unsigned* __restrict__ gh, unsigned prefix) {
    int t = threadIdx.x;
    for (int i = t; i < NBINS; i += 256) lh[i] = 0u;
    __syncthreads();
    int stride = gridDim.x * 256;
    for (int n = blockIdx.x * 256 + t; n < N4; n += stride) {
        float4 p = pred[n];
        unsigned u[4] = { __float_as_uint(p.x), __float_as_uint(p.y),
                          __float_as_uint(p.z), __float_as_uint(p.w) };
#pragma unroll
        for (int j = 0; j < 4; ++j) {
            unsigned v = u[j];
            if (PASS == 0)      atomicAdd(&lh[v >> 21], 1u);
            else if (PASS == 1) { if ((v & 0xFFE00000u) == prefix) atomicAdd(&lh[(v >> 10) & 0x7FFu], 1u); }
            else                { if ((v & 0xFFFFFC00u) == prefix) atomicAdd(&lh[v & 0x3FFu], 1u); }
        }
    }
    __syncthreads();
    for (int i = t; i < NBINS; i += 256) { unsigned v = lh[i]; if (v) atomicAdd(&gh[i], v); }
}

template <int PASS>
__device__ __forceinline__ void scan_pass(unsigned* ssum, const unsigned* __restrict__ gh,
                                          SelState* st) {
    int t = threadIdx.x;
    unsigned k = st->krem;
    unsigned local[8];
    unsigned lsum = 0;
#pragma unroll
    for (int i = 0; i < 8; ++i) { local[i] = gh[t * 8 + i]; lsum += local[i]; }
    ssum[t] = lsum;
    __syncthreads();
    unsigned val = lsum;
    for (int off = 1; off < 256; off <<= 1) {   // Hillis-Steele inclusive scan
        unsigned other = (t >= off) ? ssum[t - off] : 0u;
        __syncthreads();
        val += other;
        ssum[t] = val;
        __syncthreads();
    }
    unsigned c = val - lsum;                    // exclusive prefix of this thread's 8 bins
#pragma unroll
    for (int i = 0; i < 8; ++i) {
        if (k >= c && k < c + local[i]) {       // exactly one (t,i) matches
            unsigned bin = (unsigned)(t * 8 + i);
            if (PASS == 0)      { st->prefix = bin << 21; st->krem = k - c; }
            else if (PASS == 1) { st->prefix |= bin << 10; st->krem = k - c; }
            else                { st->threshold = fmaxf(__uint_as_float(st->prefix | bin), 0.7f); }
        }
        c += local[i];
    }
    __threadfence();
}

// ---------------- select: fast path (count>=K+1 -> thr=0.7, spec exact) or full
// cooperative 3-pass radix select + masked reduction (grid.sync between phases) ----
__global__ __launch_bounds__(256) void select_kernel(const float4* __restrict__ pred,
                                                     const float4* __restrict__ lossv,
                                                     const double* __restrict__ spec,
                                                     unsigned* __restrict__ hists,
                                                     SelState* st,
                                                     double* __restrict__ partials,
                                                     float* __restrict__ out) {
    cg::grid_group grid = cg::this_grid();
    __shared__ unsigned lh[NBINS];
    __shared__ double s1[256], s2[256];
    int t = threadIdx.x, bid = blockIdx.x;

    // Phase 0: every block redundantly sums the spec partials (32 KB, L2-resident).
    double a = 0.0, b = 0.0;
    for (int i = t; i < MAIN_BLOCKS; i += 256) { a += spec[2 * i]; b += spec[2 * i + 1]; }
    s1[t] = a; s2[t] = b;
    __syncthreads();
    for (int off = 128; off > 0; off >>= 1) {
        if (t < off) { s1[t] += s1[t + off]; s2[t] += s2[t + off]; }
        __syncthreads();
    }
    double SL = s1[0], SM = s2[0];
    if (SM >= (double)(K_RANK + 1)) {           // kth pred < 0.7 -> threshold = 0.7 exact
        if (bid == 0 && t == 0) out[0] = (float)(SL / fmax(SM, 1.0));
        return;                                 // no grid.sync ever executed on fast path
    }

    // ---- fallback: exact kth (>= 0.7) via 3-pass radix select ----
    for (int i = bid * 256 + t; i < 3 * NBINS; i += gridDim.x * 256) hists[i] = 0u;
    if (bid == 0 && t == 0) {
        st->prefix = 0u; st->krem = (unsigned)K_RANK; st->threshold = 0.7f;
        __threadfence();
    }
    grid.sync();

    hist_pass<0>(lh, pred, hists, 0u);
    grid.sync();
    if (bid == 0) scan_pass<0>(lh, hists, st);
    grid.sync();
    unsigned pfx = ((volatile SelState*)st)->prefix;

    hist_pass<1>(lh, pred, hists + NBINS, pfx);
    grid.sync();
    if (bid == 0) scan_pass<1>(lh, hists + NBINS, st);
    grid.sync();
    pfx = ((volatile SelState*)st)->prefix;

    hist_pass<2>(lh, pred, hists + 2 * NBINS, pfx);
    grid.sync();
    if (bid == 0) scan_pass<2>(lh, hists + 2 * NBINS, st);
    grid.sync();
    float thr = ((volatile SelState*)st)->threshold;

    // masked reduction at the exact threshold
    double sl = 0.0, sm = 0.0;
    for (int n = bid * 256 + t; n < N4; n += gridDim.x * 256) {
        float4 p  = pred[n];
        float4 lo = lossv[n];
        if (p.x < thr) { sl += (double)lo.x; sm += 1.0; }
        if (p.y < thr) { sl += (double)lo.y; sm += 1.0; }
        if (p.z < thr) { sl += (double)lo.z; sm += 1.0; }
        if (p.w < thr) { sl += (double)lo.w; sm += 1.0; }
    }
    s1[t] = sl; s2[t] = sm;
    __syncthreads();
    for (int off = 128; off > 0; off >>= 1) {
        if (t < off) { s1[t] += s1[t + off]; s2[t] += s2[t + off]; }
        __syncthreads();
    }
    if (t == 0) { partials[2 * bid] = s1[0]; partials[2 * bid + 1] = s2[0]; }
    __threadfence();
    grid.sync();

    if (bid == 0) {
        double x = 0.0, y = 0.0;
        for (int i = t; i < (int)gridDim.x; i += 256) { x += partials[2 * i]; y += partials[2 * i + 1]; }
        s1[t] = x; s2[t] = y;
        __syncthreads();
        for (int off = 128; off > 0; off >>= 1) {
            if (t < off) { s1[t] += s1[t + off]; s2[t] += s2[t + off]; }
            __syncthreads();
        }
        if (t == 0) out[0] = (float)(s1[0] / fmax(s2[0], 1.0));
    }
}

extern "C" void kernel_launch(void* const* d_in, const int* in_sizes, int n_in,
                              void* d_out, int out_size, void* d_ws, size_t ws_size,
                              hipStream_t stream) {
    const float4* logits = (const float4*)d_in[0];
    const float4* target = (const float4*)d_in[1];
    float* out = (float*)d_out;

    char* ws = (char*)d_ws;
    float4*   pred     = (float4*)ws;                                   // 8 MiB
    float4*   lossv    = (float4*)(ws + (size_t)N_ * 4);                // 8 MiB
    unsigned* hists    = (unsigned*)(ws + (size_t)N_ * 8);              // 24 KiB
    SelState* st       = (SelState*)(ws + (size_t)N_ * 8 + 3 * NBINS * 4);
    double*   spec     = (double*)(ws + (size_t)N_ * 8 + 3 * NBINS * 4 + 64);          // 32 KiB
    double*   partials = (double*)(ws + (size_t)N_ * 8 + 3 * NBINS * 4 + 64
                                      + (size_t)MAIN_BLOCKS * 2 * 8);                  // 8 KiB

    main_kernel<<<MAIN_BLOCKS, 256, 0, stream>>>(logits, target, pred, lossv, spec);

    void* args[] = { (void*)&pred, (void*)&lossv, (void*)&spec, (void*)&hists,
                     (void*)&st, (void*)&partials, (void*)&out };
    hipLaunchCooperativeKernel((const void*)select_kernel, dim3(SEL_BLOCKS), dim3(256),
                               args, 0, stream);
}

// Round 8
// 81.332 us; speedup vs baseline: 1.2444x; 1.0334x over previous
//
#include <hip/hip_runtime.h>
#include <hip/hip_cooperative_groups.h>

namespace cg = cooperative_groups;

#define B_ 8
#define C_ 19
#define H_ 512
#define W_ 512
#define HW_ (H_*W_)
#define N_ (B_*HW_)
#define HW4 (HW_/4)          /* 65536 float4 per channel-plane */
#define N4 (N_/4)            /* 524288 */
#define CH4 (C_*HW4)
#define K_RANK 100000
#define NBINS 2048
#define MAIN_BLOCKS (N4/512) /* 1024: 8 pixels (2 float4) per thread */
#define SEL_BLOCKS 512

struct SelState { unsigned prefix; unsigned krem; float threshold; };

typedef float f32x4 __attribute__((ext_vector_type(4)));

__device__ __forceinline__ float4 ntload(const float4* p) {
    f32x4 v = __builtin_nontemporal_load((const f32x4*)p);
    return make_float4(v.x, v.y, v.z, v.w);
}

// ---------------- main: online-softmax CE, 8 pixels/thread (2 independent groups) ------
// Two disjoint float4 pixel-groups per thread (offsets +0 and +256) updated in the same
// c-loop: doubles the independent dependence chains per instruction window so the
// scheduler can cover load latency without relying on wave count. Both groups stay
// perfectly lane-coalesced. Emits per-block partials of { sum(loss*[pred<0.7]), count }.
__global__ __launch_bounds__(256, 4) void main_kernel(const float4* __restrict__ logits,
                                                      const float4* __restrict__ target,
                                                      float4* __restrict__ pred,
                                                      float4* __restrict__ lossv,
                                                      double* __restrict__ spec) {
    int t  = threadIdx.x;
    int n4 = blockIdx.x * 512 + t;                 // group A; group B = n4 + 256
    int b   = n4 >> 16;                            // block fully inside one batch b
    int hw4 = n4 & (HW4 - 1);
    size_t base = (size_t)b * (size_t)CH4 + (size_t)hw4;
    const float4* lp = logits + base;
    const float4* tp = target + base;

    float mA[4] = {-3.4e38f,-3.4e38f,-3.4e38f,-3.4e38f};
    float mB[4] = {-3.4e38f,-3.4e38f,-3.4e38f,-3.4e38f};
    float sA[4] = {0,0,0,0}, sB[4] = {0,0,0,0};
    float tsA[4] = {0,0,0,0}, tsB[4] = {0,0,0,0};
    float tlA[4] = {0,0,0,0}, tlB[4] = {0,0,0,0};

#pragma unroll
    for (int c = 0; c < C_; ++c) {
        float4 la = ntload(lp + (size_t)c * HW4);
        float4 lb = ntload(lp + (size_t)c * HW4 + 256);
        float4 ta = ntload(tp + (size_t)c * HW4);
        float4 tb = ntload(tp + (size_t)c * HW4 + 256);
        float lav[4] = { la.x, la.y, la.z, la.w };
        float lbv[4] = { lb.x, lb.y, lb.z, lb.w };
        float tav[4] = { ta.x, ta.y, ta.z, ta.w };
        float tbv[4] = { tb.x, tb.y, tb.z, tb.w };
#pragma unroll
        for (int j = 0; j < 4; ++j) {
            float na = fmaxf(mA[j], lav[j]);
            sA[j] = fmaf(sA[j], __expf(mA[j] - na), __expf(lav[j] - na)); mA[j] = na;
            tsA[j] += tav[j];
            tlA[j] = fmaf(tav[j], lav[j], tlA[j]);
            float nb = fmaxf(mB[j], lbv[j]);
            sB[j] = fmaf(sB[j], __expf(mB[j] - nb), __expf(lbv[j] - nb)); mB[j] = nb;
            tsB[j] += tbv[j];
            tlB[j] = fmaf(tbv[j], lbv[j], tlB[j]);
        }
    }

    float loA[4], prA[4], loB[4], prB[4];
#pragma unroll
    for (int j = 0; j < 4; ++j) {
        loA[j] = tsA[j] * (mA[j] + __logf(sA[j])) - tlA[j];
        prA[j] = __expf(tlA[j] - mA[j]) / sA[j];
        loB[j] = tsB[j] * (mB[j] + __logf(sB[j])) - tlB[j];
        prB[j] = __expf(tlB[j] - mB[j]) / sB[j];
    }
    lossv[n4]       = make_float4(loA[0], loA[1], loA[2], loA[3]);
    pred[n4]        = make_float4(prA[0], prA[1], prA[2], prA[3]);
    lossv[n4 + 256] = make_float4(loB[0], loB[1], loB[2], loB[3]);
    pred[n4 + 256]  = make_float4(prB[0], prB[1], prB[2], prB[3]);

    // speculative thr == 0.7 masked partials (exact when kth < 0.7)
    double sl = 0.0, sm = 0.0;
#pragma unroll
    for (int j = 0; j < 4; ++j) {
        if (prA[j] < 0.7f) { sl += (double)loA[j]; sm += 1.0; }
        if (prB[j] < 0.7f) { sl += (double)loB[j]; sm += 1.0; }
    }
    __shared__ double sd1[256], sd2[256];
    sd1[t] = sl; sd2[t] = sm;
    __syncthreads();
    for (int off = 128; off > 0; off >>= 1) {
        if (t < off) { sd1[t] += sd1[t + off]; sd2[t] += sd2[t + off]; }
        __syncthreads();
    }
    if (t == 0) { spec[2 * blockIdx.x] = sd1[0]; spec[2 * blockIdx.x + 1] = sd2[0]; }
}

// ---------------- radix-select helpers (used only on the fallback path) ----------------
template <int PASS>
__device__ __forceinline__ void hist_pass(unsigned* lh, const float4* __restrict__ pred,
                                          unsigned* __restrict__ gh, unsigned prefix) {
    int t = threadIdx.x;
    for (int i = t; i < NBINS; i += 256) lh[i] = 0u;
    __syncthreads();
    int stride = gridDim.x * 256;
    for (int n = blockIdx.x * 256 + t; n < N4; n += stride) {
        float4 p = pred[n];
        unsigned u[4] = { __float_as_uint(p.x), __float_as_uint(p.y),
                          __float_as_uint(p.z), __float_as_uint(p.w) };
#pragma unroll
        for (int j = 0; j < 4; ++j) {
            unsigned v = u[j];
            if (PASS == 0)      atomicAdd(&lh[v >> 21], 1u);
            else if (PASS == 1) { if ((v & 0xFFE00000u) == prefix) atomicAdd(&lh[(v >> 10) & 0x7FFu], 1u); }
            else                { if ((v & 0xFFFFFC00u) == prefix) atomicAdd(&lh[v & 0x3FFu], 1u); }
        }
    }
    __syncthreads();
    for (int i = t; i < NBINS; i += 256) { unsigned v = lh[i]; if (v) atomicAdd(&gh[i], v); }
}

template <int PASS>
__device__ __forceinline__ void scan_pass(unsigned* ssum, const unsigned* __restrict__ gh,
                                          SelState* st) {
    int t = threadIdx.x;
    unsigned k = st->krem;
    unsigned local[8];
    unsigned lsum = 0;
#pragma unroll
    for (int i = 0; i < 8; ++i) { local[i] = gh[t * 8 + i]; lsum += local[i]; }
    ssum[t] = lsum;
    __syncthreads();
    unsigned val = lsum;
    for (int off = 1; off < 256; off <<= 1) {   // Hillis-Steele inclusive scan
        unsigned other = (t >= off) ? ssum[t - off] : 0u;
        __syncthreads();
        val += other;
        ssum[t] = val;
        __syncthreads();
    }
    unsigned c = val - lsum;                    // exclusive prefix of this thread's 8 bins
#pragma unroll
    for (int i = 0; i < 8; ++i) {
        if (k >= c && k < c + local[i]) {       // exactly one (t,i) matches
            unsigned bin = (unsigned)(t * 8 + i);
            if (PASS == 0)      { st->prefix = bin << 21; st->krem = k - c; }
            else if (PASS == 1) { st->prefix |= bin << 10; st->krem = k - c; }
            else                { st->threshold = fmaxf(__uint_as_float(st->prefix | bin), 0.7f); }
        }
        c += local[i];
    }
    __threadfence();
}

// ---------------- select: fast path (count>=K+1 -> thr=0.7, spec exact) or full
// cooperative 3-pass radix select + masked reduction (grid.sync between phases) ----
__global__ __launch_bounds__(256) void select_kernel(const float4* __restrict__ pred,
                                                     const float4* __restrict__ lossv,
                                                     const double* __restrict__ spec,
                                                     unsigned* __restrict__ hists,
                                                     SelState* st,
                                                     double* __restrict__ partials,
                                                     float* __restrict__ out) {
    cg::grid_group grid = cg::this_grid();
    __shared__ unsigned lh[NBINS];
    __shared__ double s1[256], s2[256];
    int t = threadIdx.x, bid = blockIdx.x;

    // Phase 0: every block redundantly sums the spec partials (16 KB, L2-resident).
    double a = 0.0, b = 0.0;
    for (int i = t; i < MAIN_BLOCKS; i += 256) { a += spec[2 * i]; b += spec[2 * i + 1]; }
    s1[t] = a; s2[t] = b;
    __syncthreads();
    for (int off = 128; off > 0; off >>= 1) {
        if (t < off) { s1[t] += s1[t + off]; s2[t] += s2[t + off]; }
        __syncthreads();
    }
    double SL = s1[0], SM = s2[0];
    if (SM >= (double)(K_RANK + 1)) {           // kth pred < 0.7 -> threshold = 0.7 exact
        if (bid == 0 && t == 0) out[0] = (float)(SL / fmax(SM, 1.0));
        return;                                 // no grid.sync ever executed on fast path
    }

    // ---- fallback: exact kth (>= 0.7) via 3-pass radix select ----
    for (int i = bid * 256 + t; i < 3 * NBINS; i += gridDim.x * 256) hists[i] = 0u;
    if (bid == 0 && t == 0) {
        st->prefix = 0u; st->krem = (unsigned)K_RANK; st->threshold = 0.7f;
        __threadfence();
    }
    grid.sync();

    hist_pass<0>(lh, pred, hists, 0u);
    grid.sync();
    if (bid == 0) scan_pass<0>(lh, hists, st);
    grid.sync();
    unsigned pfx = ((volatile SelState*)st)->prefix;

    hist_pass<1>(lh, pred, hists + NBINS, pfx);
    grid.sync();
    if (bid == 0) scan_pass<1>(lh, hists + NBINS, st);
    grid.sync();
    pfx = ((volatile SelState*)st)->prefix;

    hist_pass<2>(lh, pred, hists + 2 * NBINS, pfx);
    grid.sync();
    if (bid == 0) scan_pass<2>(lh, hists + 2 * NBINS, st);
    grid.sync();
    float thr = ((volatile SelState*)st)->threshold;

    // masked reduction at the exact threshold
    double sl = 0.0, sm = 0.0;
    for (int n = bid * 256 + t; n < N4; n += gridDim.x * 256) {
        float4 p  = pred[n];
        float4 lo = lossv[n];
        if (p.x < thr) { sl += (double)lo.x; sm += 1.0; }
        if (p.y < thr) { sl += (double)lo.y; sm += 1.0; }
        if (p.z < thr) { sl += (double)lo.z; sm += 1.0; }
        if (p.w < thr) { sl += (double)lo.w; sm += 1.0; }
    }
    s1[t] = sl; s2[t] = sm;
    __syncthreads();
    for (int off = 128; off > 0; off >>= 1) {
        if (t < off) { s1[t] += s1[t + off]; s2[t] += s2[t + off]; }
        __syncthreads();
    }
    if (t == 0) { partials[2 * bid] = s1[0]; partials[2 * bid + 1] = s2[0]; }
    __threadfence();
    grid.sync();

    if (bid == 0) {
        double x = 0.0, y = 0.0;
        for (int i = t; i < (int)gridDim.x; i += 256) { x += partials[2 * i]; y += partials[2 * i + 1]; }
        s1[t] = x; s2[t] = y;
        __syncthreads();
        for (int off = 128; off > 0; off >>= 1) {
            if (t < off) { s1[t] += s1[t + off]; s2[t] += s2[t + off]; }
            __syncthreads();
        }
        if (t == 0) out[0] = (float)(s1[0] / fmax(s2[0], 1.0));
    }
}

extern "C" void kernel_launch(void* const* d_in, const int* in_sizes, int n_in,
                              void* d_out, int out_size, void* d_ws, size_t ws_size,
                              hipStream_t stream) {
    const float4* logits = (const float4*)d_in[0];
    const float4* target = (const float4*)d_in[1];
    float* out = (float*)d_out;

    char* ws = (char*)d_ws;
    float4*   pred     = (float4*)ws;                                   // 8 MiB
    float4*   lossv    = (float4*)(ws + (size_t)N_ * 4);                // 8 MiB
    unsigned* hists    = (unsigned*)(ws + (size_t)N_ * 8);              // 24 KiB
    SelState* st       = (SelState*)(ws + (size_t)N_ * 8 + 3 * NBINS * 4);
    double*   spec     = (double*)(ws + (size_t)N_ * 8 + 3 * NBINS * 4 + 64);          // 16 KiB
    double*   partials = (double*)(ws + (size_t)N_ * 8 + 3 * NBINS * 4 + 64
                                      + (size_t)MAIN_BLOCKS * 2 * 8);                  // 8 KiB

    main_kernel<<<MAIN_BLOCKS, 256, 0, stream>>>(logits, target, pred, lossv, spec);

    void* args[] = { (void*)&pred, (void*)&lossv, (void*)&spec, (void*)&hists,
                     (void*)&st, (void*)&partials, (void*)&out };
    hipLaunchCooperativeKernel((const void*)select_kernel, dim3(SEL_BLOCKS), dim3(256),
                               args, 0, stream);
}